// Round 2
// baseline (700.169 us; speedup 1.0000x reference)
//
#include <hip/hip_runtime.h>
#include <hip/hip_bf16.h>
#include <stdint.h>

typedef __attribute__((ext_vector_type(8))) short short8;
typedef __attribute__((ext_vector_type(4))) float f32x4;
using bf16 = __hip_bfloat16;

#define MFMA16(a, b, c) __builtin_amdgcn_mfma_f32_16x16x32_bf16((a), (b), (c), 0, 0, 0)

__device__ __forceinline__ float rmax16(float v) {
  v = fmaxf(v, __shfl_xor(v, 1, 64));
  v = fmaxf(v, __shfl_xor(v, 2, 64));
  v = fmaxf(v, __shfl_xor(v, 4, 64));
  v = fmaxf(v, __shfl_xor(v, 8, 64));
  return v;
}
__device__ __forceinline__ float rsum16(float v) {
  v += __shfl_xor(v, 1, 64);
  v += __shfl_xor(v, 2, 64);
  v += __shfl_xor(v, 4, 64);
  v += __shfl_xor(v, 8, 64);
  return v;
}

// Adaptive 8-element load: bf16 direct, or f32 -> bf16 convert.
__device__ __forceinline__ short8 load8(const void* base, size_t eoff, int isbf) {
  if (isbf) {
    return *(const short8*)((const bf16*)base + eoff);
  } else {
    const float* f = (const float*)base + eoff;
    float4 a = *(const float4*)f;
    float4 b = *(const float4*)(f + 4);
    union { bf16 h[8]; short8 s; } u;
    u.h[0] = __float2bfloat16(a.x); u.h[1] = __float2bfloat16(a.y);
    u.h[2] = __float2bfloat16(a.z); u.h[3] = __float2bfloat16(a.w);
    u.h[4] = __float2bfloat16(b.x); u.h[5] = __float2bfloat16(b.y);
    u.h[6] = __float2bfloat16(b.z); u.h[7] = __float2bfloat16(b.w);
    return u.s;
  }
}

// ================= dtype detect =================
// Interpret first 4096 halfwords of x as bf16. Real bf16 N(0,1) data: max|v| < 100.
// f32 bit patterns: low-half garbage bf16s exceed 100 w.p. ~1. flag=1 -> bf16 inputs.
__global__ void detect_dtype(const unsigned short* __restrict__ xb, int* __restrict__ flag) {
  __shared__ unsigned smax[4];
  unsigned m = 0;
  for (int i = threadIdx.x; i < 4096; i += 256) {
    unsigned ab = (((unsigned)xb[i]) << 16) & 0x7FFFFFFFu;
    m = ab > m ? ab : m;
  }
#pragma unroll
  for (int d = 1; d < 64; d <<= 1) {
    unsigned o = (unsigned)__shfl_xor((int)m, d, 64);
    m = o > m ? o : m;
  }
  if ((threadIdx.x & 63) == 0) smax[threadIdx.x >> 6] = m;
  __syncthreads();
  if (threadIdx.x == 0) {
    unsigned mm = smax[0];
    for (int i = 1; i < 4; ++i) mm = smax[i] > mm ? smax[i] : mm;
    *flag = (mm < 0x42C80000u) ? 1 : 0;  // 100.0f threshold
  }
}

// ================= GEMM: C = A(MxK) @ B(KxN), row-major =================
// a_fol/b_fol: operand dtype follows flag (else always bf16).
// c_fol: when set and flag==0, emit f32 output.
__global__ __launch_bounds__(256) void gemm_rr(const void* __restrict__ A,
                                               const void* __restrict__ B,
                                               void* __restrict__ C,
                                               int M, int N, int K,
                                               const int* __restrict__ flag,
                                               int a_fol, int b_fol, int c_fol)
{
  __shared__ __align__(16) bf16 As[128][40];   // [m][k], pad 32->40
  __shared__ __align__(16) bf16 Bt[128][40];   // [n][k] (B transposed), pad

  const int isbf = *flag;
  const int abf = a_fol ? isbf : 1;
  const int bbf = b_fol ? isbf : 1;
  const int cf32 = c_fol && !isbf;

  const int tid  = threadIdx.x;
  const int lane = tid & 63;
  const int w    = tid >> 6;
  const int wm   = (w >> 1) * 64;
  const int wn   = (w & 1) * 64;
  const int l15  = lane & 15;
  const int lhi  = lane >> 4;
  const int bm0  = blockIdx.y * 128;
  const int bn0  = blockIdx.x * 128;

  f32x4 acc[4][4];
  const f32x4 zero4 = {0.f, 0.f, 0.f, 0.f};
#pragma unroll
  for (int i = 0; i < 4; ++i)
#pragma unroll
    for (int j = 0; j < 4; ++j) acc[i][j] = zero4;

  for (int k0 = 0; k0 < K; k0 += 32) {
#pragma unroll
    for (int p = 0; p < 2; ++p) {
      int flat = (p * 256 + tid) * 8;
      int r = flat >> 5, c = flat & 31;
      short8 v = load8(A, (size_t)(bm0 + r) * K + k0 + c, abf);
      *(short8*)(&As[r][c]) = v;
    }
#pragma unroll
    for (int p = 0; p < 2; ++p) {
      int flat = (p * 256 + tid) * 8;
      int kk = flat >> 7, n = flat & 127;
      short8 v = load8(B, (size_t)(k0 + kk) * N + bn0 + n, bbf);
#pragma unroll
      for (int j = 0; j < 8; ++j) Bt[n + j][kk] = ((const bf16*)&v)[j];
    }
    __syncthreads();

    short8 a[4], b[4];
#pragma unroll
    for (int mt = 0; mt < 4; ++mt)
      a[mt] = *(const short8*)(&As[wm + mt * 16 + l15][lhi * 8]);
#pragma unroll
    for (int nt = 0; nt < 4; ++nt)
      b[nt] = *(const short8*)(&Bt[wn + nt * 16 + l15][lhi * 8]);
#pragma unroll
    for (int mt = 0; mt < 4; ++mt)
#pragma unroll
      for (int nt = 0; nt < 4; ++nt)
        acc[mt][nt] = MFMA16(a[mt], b[nt], acc[mt][nt]);
    __syncthreads();
  }

  // epilogue: D layout col = lane&15, row = (lane>>4)*4 + r
#pragma unroll
  for (int mt = 0; mt < 4; ++mt) {
    int row0 = bm0 + wm + mt * 16 + lhi * 4;
#pragma unroll
    for (int nt = 0; nt < 4; ++nt) {
      int col = bn0 + wn + nt * 16 + l15;
#pragma unroll
      for (int r = 0; r < 4; ++r) {
        float val = acc[mt][nt][r];
        size_t idx = (size_t)(row0 + r) * N + col;
        if (cf32) ((float*)C)[idx] = val;
        else ((bf16*)C)[idx] = __float2bfloat16(val);
      }
    }
  }
}

// ================= RoPE (in-place on ws Q/K bf16 buffers) =================
__global__ void rope_kernel(bf16* __restrict__ Q, bf16* __restrict__ Kb)
{
  const int NQ = 2048 * 16 * 64;
  const int NK = 2048 * 4 * 64;
  int idx = blockIdx.x * blockDim.x + threadIdx.x;
  bf16* base;
  int s, d;
  if (idx < NQ) {
    s = idx / (16 * 64);
    int rem = idx - s * (16 * 64);
    int h = rem >> 6;
    d = rem & 63;
    base = Q + (size_t)s * 2048 + h * 128 + d;
  } else {
    int i2 = idx - NQ;
    if (i2 >= NK) return;
    s = i2 / (4 * 64);
    int rem = i2 - s * (4 * 64);
    int h = rem >> 6;
    d = rem & 63;
    base = Kb + (size_t)s * 512 + h * 128 + d;
  }
  float inv = expf(-(float)d * (9.210340371976184f / 64.0f));
  float ang = (float)s * inv;
  float c = cosf(ang), sn = sinf(ang);
  float x1 = __bfloat162float(base[0]);
  float x2 = __bfloat162float(base[64]);
  base[0]  = __float2bfloat16(x1 * c - x2 * sn);
  base[64] = __float2bfloat16(x2 * c + x1 * sn);
}

// ================= Differential sliding-window attention =================
__global__ __launch_bounds__(256) void diff_attn(const bf16* __restrict__ Q,
                                                 const bf16* __restrict__ Kg,
                                                 const bf16* __restrict__ Vg,
                                                 const void* __restrict__ lam,
                                                 bf16* __restrict__ O,
                                                 const int* __restrict__ flag)
{
  __shared__ __align__(16) bf16 Ks[64][136];
  __shared__ __align__(16) bf16 Vt[128][72];
  __shared__ __align__(16) bf16 Pw[4][16][72];

  const int isbf = *flag;
  const int qb   = blockIdx.x;
  const int h    = blockIdx.y;
  const int kvh  = h >> 2;
  const int tid  = threadIdx.x;
  const int lane = tid & 63;
  const int w    = tid >> 6;
  const int l15  = lane & 15;
  const int lhi  = lane >> 4;
  const int qg   = qb * 64 + w * 16;
  const float lamv = isbf ? __bfloat162float(((const bf16*)lam)[h])
                          : ((const float*)lam)[h];

  short8 qf[4];
  {
    const bf16* qrow = Q + (size_t)(qg + l15) * 2048 + h * 128;
#pragma unroll
    for (int c = 0; c < 4; ++c)
      qf[c] = *(const short8*)(qrow + c * 32 + lhi * 8);
  }

  const int t0 = (qb >= 8) ? (qb - 8) : 0;

  float m1[4], l1[4], m2[4], l2[4], den[4];
  f32x4 accv[8];
  const f32x4 zero4 = {0.f, 0.f, 0.f, 0.f};
#pragma unroll
  for (int r = 0; r < 4; ++r) { m1[r] = m2[r] = -1e30f; l1[r] = l2[r] = 0.f; den[r] = 0.f; }
#pragma unroll
  for (int n = 0; n < 8; ++n) accv[n] = zero4;

  // pass 1: softmax stats
  for (int t = t0; t <= qb; ++t) {
    const int kbase = t * 64;
#pragma unroll
    for (int p = 0; p < 4; ++p) {
      int flat = (p * 256 + tid) * 8;
      int r = flat >> 7, c = flat & 127;
      *(short8*)(&Ks[r][c]) = *(const short8*)(Kg + (size_t)(kbase + r) * 512 + kvh * 128 + c);
    }
    __syncthreads();
#pragma unroll
    for (int nt = 0; nt < 4; ++nt) {
      short8 k0 = *(const short8*)(&Ks[nt * 16 + l15][0  + lhi * 8]);
      short8 k1 = *(const short8*)(&Ks[nt * 16 + l15][32 + lhi * 8]);
      short8 k2 = *(const short8*)(&Ks[nt * 16 + l15][64 + lhi * 8]);
      short8 k3 = *(const short8*)(&Ks[nt * 16 + l15][96 + lhi * 8]);
      f32x4 s1 = zero4, s2 = zero4;
      s1 = MFMA16(qf[0], k0, s1);
      s1 = MFMA16(qf[1], k1, s1);
      s2 = MFMA16(qf[2], k2, s2);
      s2 = MFMA16(qf[3], k3, s2);
      const int key = kbase + nt * 16 + l15;
#pragma unroll
      for (int r = 0; r < 4; ++r) {
        const int qrow = qg + lhi * 4 + r;
        const bool ok = (key <= qrow) && (key >= qrow - 511);
        float v1 = ok ? s1[r] * 0.125f : -1e30f;
        float v2 = ok ? s2[r] * 0.125f : -1e30f;
        float t1 = rmax16(v1);
        float t2 = rmax16(v2);
        float nm1 = fmaxf(m1[r], t1);
        float nm2 = fmaxf(m2[r], t2);
        float e1 = rsum16(ok ? __expf(v1 - nm1) : 0.f);
        float e2 = rsum16(ok ? __expf(v2 - nm2) : 0.f);
        l1[r] = l1[r] * __expf(m1[r] - nm1) + e1;
        l2[r] = l2[r] * __expf(m2[r] - nm2) + e2;
        m1[r] = nm1;
        m2[r] = nm2;
      }
    }
    __syncthreads();
  }

  float rl1[4], rl2[4];
#pragma unroll
  for (int r = 0; r < 4; ++r) { rl1[r] = 1.f / l1[r]; rl2[r] = 1.f / l2[r]; }

  // pass 2: p = relu(a1 - lam*a2), den += sum p, num += p @ V
  for (int t = t0; t <= qb; ++t) {
    const int kbase = t * 64;
#pragma unroll
    for (int p = 0; p < 4; ++p) {
      int flat = (p * 256 + tid) * 8;
      int r = flat >> 7, c = flat & 127;
      *(short8*)(&Ks[r][c]) = *(const short8*)(Kg + (size_t)(kbase + r) * 512 + kvh * 128 + c);
      short8 v = *(const short8*)(Vg + (size_t)(kbase + r) * 512 + kvh * 128 + c);
#pragma unroll
      for (int j = 0; j < 8; ++j) Vt[c + j][r] = ((const bf16*)&v)[j];
    }
    __syncthreads();
#pragma unroll
    for (int nt = 0; nt < 4; ++nt) {
      short8 k0 = *(const short8*)(&Ks[nt * 16 + l15][0  + lhi * 8]);
      short8 k1 = *(const short8*)(&Ks[nt * 16 + l15][32 + lhi * 8]);
      short8 k2 = *(const short8*)(&Ks[nt * 16 + l15][64 + lhi * 8]);
      short8 k3 = *(const short8*)(&Ks[nt * 16 + l15][96 + lhi * 8]);
      f32x4 s1 = zero4, s2 = zero4;
      s1 = MFMA16(qf[0], k0, s1);
      s1 = MFMA16(qf[1], k1, s1);
      s2 = MFMA16(qf[2], k2, s2);
      s2 = MFMA16(qf[3], k3, s2);
      const int key = kbase + nt * 16 + l15;
#pragma unroll
      for (int r = 0; r < 4; ++r) {
        const int qrow = qg + lhi * 4 + r;
        const bool ok = (key <= qrow) && (key >= qrow - 511);
        float a1 = ok ? __expf(s1[r] * 0.125f - m1[r]) * rl1[r] : 0.f;
        float a2 = ok ? __expf(s2[r] * 0.125f - m2[r]) * rl2[r] : 0.f;
        float p = a1 - lamv * a2;
        p = p > 0.f ? p : 0.f;
        den[r] += rsum16(p);
        Pw[w][lhi * 4 + r][nt * 16 + l15] = __float2bfloat16(p);
      }
    }
    __syncthreads();
#pragma unroll
    for (int kc = 0; kc < 2; ++kc) {
      short8 pa = *(const short8*)(&Pw[w][l15][kc * 32 + lhi * 8]);
#pragma unroll
      for (int n = 0; n < 8; ++n) {
        short8 vb = *(const short8*)(&Vt[n * 16 + l15][kc * 32 + lhi * 8]);
        accv[n] = MFMA16(pa, vb, accv[n]);
      }
    }
    __syncthreads();
  }

#pragma unroll
  for (int n = 0; n < 8; ++n) {
    int col = h * 128 + n * 16 + l15;
#pragma unroll
    for (int r = 0; r < 4; ++r) {
      int qrow = qg + lhi * 4 + r;
      float o = accv[n][r] / (den[r] + 1e-6f);
      O[(size_t)qrow * 2048 + col] = __float2bfloat16(o);
    }
  }
}

// ================= launch =================
extern "C" void kernel_launch(void* const* d_in, const int* in_sizes, int n_in,
                              void* d_out, int out_size, void* d_ws, size_t ws_size,
                              hipStream_t stream)
{
  char* ws = (char*)d_ws;
  int*  flag = (int*)ws;
  bf16* Qb   = (bf16*)(ws + 1u  * (1u << 20));  // 8 MB
  bf16* Kb   = (bf16*)(ws + 9u  * (1u << 20));  // 2 MB
  bf16* Vb   = (bf16*)(ws + 11u * (1u << 20));  // 2 MB
  bf16* ATT  = (bf16*)(ws + 13u * (1u << 20));  // 8 MB  (total 21 MB)

  detect_dtype<<<1, 256, 0, stream>>>((const unsigned short*)d_in[0], flag);
  gemm_rr<<<dim3(16, 16), 256, 0, stream>>>(d_in[0], d_in[1], Qb, 2048, 2048, 2048, flag, 1, 1, 0);
  gemm_rr<<<dim3(4, 16),  256, 0, stream>>>(d_in[0], d_in[2], Kb, 2048, 512,  2048, flag, 1, 1, 0);
  gemm_rr<<<dim3(4, 16),  256, 0, stream>>>(d_in[0], d_in[3], Vb, 2048, 512,  2048, flag, 1, 1, 0);
  rope_kernel<<<10240, 256, 0, stream>>>(Qb, Kb);
  diff_attn<<<dim3(32, 16), 256, 0, stream>>>(Qb, Kb, Vb, d_in[5], ATT, flag);
  gemm_rr<<<dim3(16, 16), 256, 0, stream>>>(ATT, d_in[4], d_out, 2048, 2048, 2048, flag, 0, 1, 1);
}

// Round 3
// 267.445 us; speedup vs baseline: 2.6180x; 2.6180x over previous
//
#include <hip/hip_runtime.h>
#include <hip/hip_bf16.h>
#include <stdint.h>

typedef __attribute__((ext_vector_type(8))) short short8;
typedef __attribute__((ext_vector_type(4))) float f32x4;
using bf16 = __hip_bfloat16;

#define MFMA16(a, b, c) __builtin_amdgcn_mfma_f32_16x16x32_bf16((a), (b), (c), 0, 0, 0)

#define GLOAD_LDS16(g, l) __builtin_amdgcn_global_load_lds( \
    (const __attribute__((address_space(1))) void*)(g),     \
    (__attribute__((address_space(3))) void*)(l), 16, 0, 0)

__device__ __forceinline__ float rmax16(float v) {
  v = fmaxf(v, __shfl_xor(v, 1, 64));
  v = fmaxf(v, __shfl_xor(v, 2, 64));
  v = fmaxf(v, __shfl_xor(v, 4, 64));
  v = fmaxf(v, __shfl_xor(v, 8, 64));
  return v;
}
__device__ __forceinline__ float rsum16(float v) {
  v += __shfl_xor(v, 1, 64);
  v += __shfl_xor(v, 2, 64);
  v += __shfl_xor(v, 4, 64);
  v += __shfl_xor(v, 8, 64);
  return v;
}

// ================= f32 -> bf16 convert (x) =================
__global__ __launch_bounds__(256) void conv_bf16(const float* __restrict__ in,
                                                 bf16* __restrict__ out, int n8)
{
  int i = blockIdx.x * blockDim.x + threadIdx.x;
  if (i >= n8) return;
  const float* f = in + (size_t)i * 8;
  float4 a = *(const float4*)f;
  float4 b = *(const float4*)(f + 4);
  union { bf16 h[8]; short8 s; } u;
  u.h[0] = __float2bfloat16(a.x); u.h[1] = __float2bfloat16(a.y);
  u.h[2] = __float2bfloat16(a.z); u.h[3] = __float2bfloat16(a.w);
  u.h[4] = __float2bfloat16(b.x); u.h[5] = __float2bfloat16(b.y);
  u.h[6] = __float2bfloat16(b.z); u.h[7] = __float2bfloat16(b.w);
  *(short8*)(out + (size_t)i * 8) = u.s;
}

// ================= f32 [K][N] -> bf16 transposed [N][ldt] =================
// 64x64 tiles via LDS. grid = (N/64, K/64).
__global__ __launch_bounds__(256) void transpose_conv(const float* __restrict__ W,
                                                      bf16* __restrict__ Wt,
                                                      int N, int ldt)
{
  __shared__ bf16 t[64][72];
  const int tid = threadIdx.x;
  const int n0 = blockIdx.x * 64;
  const int k0 = blockIdx.y * 64;
  // load 64x64 f32 (coalesced), store transposed into LDS as bf16
#pragma unroll
  for (int pass = 0; pass < 4; ++pass) {
    int r = pass * 16 + (tid >> 4);        // k offset
    int c = (tid & 15) * 4;                // n offset
    float4 v = *(const float4*)(W + (size_t)(k0 + r) * N + n0 + c);
    t[c + 0][r] = __float2bfloat16(v.x);
    t[c + 1][r] = __float2bfloat16(v.y);
    t[c + 2][r] = __float2bfloat16(v.z);
    t[c + 3][r] = __float2bfloat16(v.w);
  }
  __syncthreads();
  // write coalesced: Wt[n][k] 16B per thread
#pragma unroll
  for (int pass = 0; pass < 2; ++pass) {
    int n = pass * 32 + (tid >> 3);
    int k8 = (tid & 7) * 8;
    *(short8*)(Wt + (size_t)(n0 + n) * ldt + k0 + k8) = *(const short8*)(&t[n][k8]);
  }
}

// ================= GEMM: C = A(MxK) @ Bt(NxK)^T, bf16 via global_load_lds =================
// 128x128 tile, BK=32, 4 waves (2x2), each wave 64x64 via 4x4 of 16x16x32 mfma.
template <int CF32>
__global__ __launch_bounds__(256) void gemm_bt(const bf16* __restrict__ A,
                                               const bf16* __restrict__ Bt,
                                               void* __restrict__ C,
                                               int M, int N, int K)
{
  __shared__ __align__(16) bf16 As[128 * 32];
  __shared__ __align__(16) bf16 Bs[128 * 32];

  const int tid  = threadIdx.x;
  const int lane = tid & 63;
  const int w    = tid >> 6;
  const int wm   = (w >> 1) * 64;
  const int wn   = (w & 1) * 64;
  const int l15  = lane & 15;
  const int lhi  = lane >> 4;
  const int bm0  = blockIdx.y * 128;
  const int bn0  = blockIdx.x * 128;

  f32x4 acc[4][4];
  const f32x4 zero4 = {0.f, 0.f, 0.f, 0.f};
#pragma unroll
  for (int i = 0; i < 4; ++i)
#pragma unroll
    for (int j = 0; j < 4; ++j) acc[i][j] = zero4;

  for (int k0 = 0; k0 < K; k0 += 32) {
    // stage A/B tiles: linear LDS [128][32], 16B per lane per issue
#pragma unroll
    for (int p = 0; p < 2; ++p) {
      int flat16 = (p * 4 + w) * 64 + lane;        // 16B-chunk index 0..511
      int row = flat16 >> 2;
      int col = (flat16 & 3) * 8;
      GLOAD_LDS16(A  + (size_t)(bm0 + row) * K + k0 + col, As + flat16 * 8);
      GLOAD_LDS16(Bt + (size_t)(bn0 + row) * K + k0 + col, Bs + flat16 * 8);
    }
    __syncthreads();

    short8 a[4], b[4];
#pragma unroll
    for (int mt = 0; mt < 4; ++mt)
      a[mt] = *(const short8*)(As + (wm + mt * 16 + l15) * 32 + lhi * 8);
#pragma unroll
    for (int nt = 0; nt < 4; ++nt)
      b[nt] = *(const short8*)(Bs + (wn + nt * 16 + l15) * 32 + lhi * 8);
#pragma unroll
    for (int mt = 0; mt < 4; ++mt)
#pragma unroll
      for (int nt = 0; nt < 4; ++nt)
        acc[mt][nt] = MFMA16(a[mt], b[nt], acc[mt][nt]);
    __syncthreads();
  }

  // epilogue: D layout col = lane&15, row = (lane>>4)*4 + r
#pragma unroll
  for (int mt = 0; mt < 4; ++mt) {
    int row0 = bm0 + wm + mt * 16 + lhi * 4;
#pragma unroll
    for (int nt = 0; nt < 4; ++nt) {
      int col = bn0 + wn + nt * 16 + l15;
#pragma unroll
      for (int r = 0; r < 4; ++r) {
        float val = acc[mt][nt][r];
        size_t idx = (size_t)(row0 + r) * N + col;
        if (CF32) ((float*)C)[idx] = val;
        else ((bf16*)C)[idx] = __float2bfloat16(val);
      }
    }
  }
}

// ================= RoPE (in-place on QKV [2048][3072] bf16) =================
__global__ void rope_kernel(bf16* __restrict__ QKV)
{
  const int NQ = 2048 * 16 * 64;
  const int NK = 2048 * 4 * 64;
  int idx = blockIdx.x * blockDim.x + threadIdx.x;
  bf16* base;
  int s, d;
  if (idx < NQ) {
    s = idx / (16 * 64);
    int rem = idx - s * (16 * 64);
    int h = rem >> 6;
    d = rem & 63;
    base = QKV + (size_t)s * 3072 + h * 128 + d;
  } else {
    int i2 = idx - NQ;
    if (i2 >= NK) return;
    s = i2 / (4 * 64);
    int rem = i2 - s * (4 * 64);
    int h = rem >> 6;
    d = rem & 63;
    base = QKV + (size_t)s * 3072 + 2048 + h * 128 + d;
  }
  float inv = expf(-(float)d * (9.210340371976184f / 64.0f));
  float ang = (float)s * inv;
  float c = cosf(ang), sn = sinf(ang);
  float x1 = __bfloat162float(base[0]);
  float x2 = __bfloat162float(base[64]);
  base[0]  = __float2bfloat16(x1 * c - x2 * sn);
  base[64] = __float2bfloat16(x2 * c + x1 * sn);
}

// ================= Differential sliding-window attention =================
// QKV: [2048][3072] bf16 (Q at +0, K at +2048, V at +2560). O: [2048][2048] bf16.
__global__ __launch_bounds__(256) void diff_attn(const bf16* __restrict__ QKV,
                                                 const float* __restrict__ lam,
                                                 bf16* __restrict__ O)
{
  __shared__ __align__(16) bf16 Ks[64][136];
  __shared__ __align__(16) bf16 Vt[128][72];
  __shared__ __align__(16) bf16 Pw[4][16][72];

  const int qb   = blockIdx.x;
  const int h    = blockIdx.y;
  const int kvh  = h >> 2;
  const int tid  = threadIdx.x;
  const int lane = tid & 63;
  const int w    = tid >> 6;
  const int l15  = lane & 15;
  const int lhi  = lane >> 4;
  const int qg   = qb * 64 + w * 16;
  const float lamv = lam[h];

  const bf16* Kg = QKV + 2048 + (size_t)kvh * 128;
  const bf16* Vg = QKV + 2560 + (size_t)kvh * 128;

  short8 qf[4];
  {
    const bf16* qrow = QKV + (size_t)(qg + l15) * 3072 + h * 128;
#pragma unroll
    for (int c = 0; c < 4; ++c)
      qf[c] = *(const short8*)(qrow + c * 32 + lhi * 8);
  }

  const int t0 = (qb >= 8) ? (qb - 8) : 0;

  float m1[4], l1[4], m2[4], l2[4], den[4];
  f32x4 accv[8];
  const f32x4 zero4 = {0.f, 0.f, 0.f, 0.f};
#pragma unroll
  for (int r = 0; r < 4; ++r) { m1[r] = m2[r] = -1e30f; l1[r] = l2[r] = 0.f; den[r] = 0.f; }
#pragma unroll
  for (int n = 0; n < 8; ++n) accv[n] = zero4;

  // pass 1: softmax stats
  for (int t = t0; t <= qb; ++t) {
    const int kbase = t * 64;
#pragma unroll
    for (int p = 0; p < 4; ++p) {
      int flat = (p * 256 + tid) * 8;
      int r = flat >> 7, c = flat & 127;
      *(short8*)(&Ks[r][c]) = *(const short8*)(Kg + (size_t)(kbase + r) * 3072 + c);
    }
    __syncthreads();
#pragma unroll
    for (int nt = 0; nt < 4; ++nt) {
      short8 k0 = *(const short8*)(&Ks[nt * 16 + l15][0  + lhi * 8]);
      short8 k1 = *(const short8*)(&Ks[nt * 16 + l15][32 + lhi * 8]);
      short8 k2 = *(const short8*)(&Ks[nt * 16 + l15][64 + lhi * 8]);
      short8 k3 = *(const short8*)(&Ks[nt * 16 + l15][96 + lhi * 8]);
      f32x4 s1 = zero4, s2 = zero4;
      s1 = MFMA16(qf[0], k0, s1);
      s1 = MFMA16(qf[1], k1, s1);
      s2 = MFMA16(qf[2], k2, s2);
      s2 = MFMA16(qf[3], k3, s2);
      const int key = kbase + nt * 16 + l15;
#pragma unroll
      for (int r = 0; r < 4; ++r) {
        const int qrow = qg + lhi * 4 + r;
        const bool ok = (key <= qrow) && (key >= qrow - 511);
        float v1 = ok ? s1[r] * 0.125f : -1e30f;
        float v2 = ok ? s2[r] * 0.125f : -1e30f;
        float t1 = rmax16(v1);
        float t2 = rmax16(v2);
        float nm1 = fmaxf(m1[r], t1);
        float nm2 = fmaxf(m2[r], t2);
        float e1 = rsum16(ok ? __expf(v1 - nm1) : 0.f);
        float e2 = rsum16(ok ? __expf(v2 - nm2) : 0.f);
        l1[r] = l1[r] * __expf(m1[r] - nm1) + e1;
        l2[r] = l2[r] * __expf(m2[r] - nm2) + e2;
        m1[r] = nm1;
        m2[r] = nm2;
      }
    }
    __syncthreads();
  }

  float rl1[4], rl2[4];
#pragma unroll
  for (int r = 0; r < 4; ++r) { rl1[r] = 1.f / l1[r]; rl2[r] = 1.f / l2[r]; }

  // pass 2: p = relu(a1 - lam*a2), den += sum p, num += p @ V
  for (int t = t0; t <= qb; ++t) {
    const int kbase = t * 64;
#pragma unroll
    for (int p = 0; p < 4; ++p) {
      int flat = (p * 256 + tid) * 8;
      int r = flat >> 7, c = flat & 127;
      *(short8*)(&Ks[r][c]) = *(const short8*)(Kg + (size_t)(kbase + r) * 3072 + c);
      short8 v = *(const short8*)(Vg + (size_t)(kbase + r) * 3072 + c);
#pragma unroll
      for (int j = 0; j < 8; ++j) Vt[c + j][r] = ((const bf16*)&v)[j];
    }
    __syncthreads();
#pragma unroll
    for (int nt = 0; nt < 4; ++nt) {
      short8 k0 = *(const short8*)(&Ks[nt * 16 + l15][0  + lhi * 8]);
      short8 k1 = *(const short8*)(&Ks[nt * 16 + l15][32 + lhi * 8]);
      short8 k2 = *(const short8*)(&Ks[nt * 16 + l15][64 + lhi * 8]);
      short8 k3 = *(const short8*)(&Ks[nt * 16 + l15][96 + lhi * 8]);
      f32x4 s1 = zero4, s2 = zero4;
      s1 = MFMA16(qf[0], k0, s1);
      s1 = MFMA16(qf[1], k1, s1);
      s2 = MFMA16(qf[2], k2, s2);
      s2 = MFMA16(qf[3], k3, s2);
      const int key = kbase + nt * 16 + l15;
#pragma unroll
      for (int r = 0; r < 4; ++r) {
        const int qrow = qg + lhi * 4 + r;
        const bool ok = (key <= qrow) && (key >= qrow - 511);
        float a1 = ok ? __expf(s1[r] * 0.125f - m1[r]) * rl1[r] : 0.f;
        float a2 = ok ? __expf(s2[r] * 0.125f - m2[r]) * rl2[r] : 0.f;
        float p = a1 - lamv * a2;
        p = p > 0.f ? p : 0.f;
        den[r] += rsum16(p);
        Pw[w][lhi * 4 + r][nt * 16 + l15] = __float2bfloat16(p);
      }
    }
    __syncthreads();
#pragma unroll
    for (int kc = 0; kc < 2; ++kc) {
      short8 pa = *(const short8*)(&Pw[w][l15][kc * 32 + lhi * 8]);
#pragma unroll
      for (int n = 0; n < 8; ++n) {
        short8 vb = *(const short8*)(&Vt[n * 16 + l15][kc * 32 + lhi * 8]);
        accv[n] = MFMA16(pa, vb, accv[n]);
      }
    }
    __syncthreads();
  }

#pragma unroll
  for (int n = 0; n < 8; ++n) {
    int col = h * 128 + n * 16 + l15;
#pragma unroll
    for (int r = 0; r < 4; ++r) {
      int qrow = qg + lhi * 4 + r;
      float o = accv[n][r] / (den[r] + 1e-6f);
      O[(size_t)qrow * 2048 + col] = __float2bfloat16(o);
    }
  }
}

// ================= launch =================
extern "C" void kernel_launch(void* const* d_in, const int* in_sizes, int n_in,
                              void* d_out, int out_size, void* d_ws, size_t ws_size,
                              hipStream_t stream)
{
  const float* x   = (const float*)d_in[0];
  const float* Wq  = (const float*)d_in[1];
  const float* Wk  = (const float*)d_in[2];
  const float* Wv  = (const float*)d_in[3];
  const float* Wo  = (const float*)d_in[4];
  const float* lam = (const float*)d_in[5];

  char* ws = (char*)d_ws;
  bf16* xb    = (bf16*)(ws);                       // [2048][2048]  8 MB
  bf16* Wqkvt = (bf16*)(ws + 8ull  * (1u << 20));  // [3072][2048] 12 MB
  bf16* Wot   = (bf16*)(ws + 20ull * (1u << 20));  // [2048][2048]  8 MB
  bf16* QKV   = (bf16*)(ws + 28ull * (1u << 20));  // [2048][3072] 12 MB
  bf16* ATT   = (bf16*)(ws + 40ull * (1u << 20));  // [2048][2048]  8 MB (total 48 MB)

  conv_bf16<<<2048, 256, 0, stream>>>(x, xb, 2048 * 2048 / 8);
  transpose_conv<<<dim3(32, 32), 256, 0, stream>>>(Wq, Wqkvt,                2048, 2048);
  transpose_conv<<<dim3(8,  32), 256, 0, stream>>>(Wk, Wqkvt + 2048 * 2048,  512, 2048);
  transpose_conv<<<dim3(8,  32), 256, 0, stream>>>(Wv, Wqkvt + 2560 * 2048,  512, 2048);
  transpose_conv<<<dim3(32, 32), 256, 0, stream>>>(Wo, Wot,                 2048, 2048);

  gemm_bt<0><<<dim3(24, 16), 256, 0, stream>>>(xb, Wqkvt, QKV, 2048, 3072, 2048);
  rope_kernel<<<10240, 256, 0, stream>>>(QKV);
  diff_attn<<<dim3(32, 16), 256, 0, stream>>>(QKV, lam, ATT);
  gemm_bt<1><<<dim3(16, 16), 256, 0, stream>>>(ATT, Wot, d_out, 2048, 2048, 2048);
}

// Round 4
// 176.998 us; speedup vs baseline: 3.9558x; 1.5110x over previous
//
#include <hip/hip_runtime.h>
#include <hip/hip_bf16.h>
#include <stdint.h>

typedef __attribute__((ext_vector_type(8))) short short8;
typedef __attribute__((ext_vector_type(4))) float f32x4;
using bf16 = __hip_bfloat16;

#define MFMA16(a, b, c) __builtin_amdgcn_mfma_f32_16x16x32_bf16((a), (b), (c), 0, 0, 0)

#define GLOAD_LDS16(g, l) __builtin_amdgcn_global_load_lds( \
    (const __attribute__((address_space(1))) void*)(g),     \
    (__attribute__((address_space(3))) void*)(l), 16, 0, 0)

__device__ __forceinline__ unsigned packbf2(float lo, float hi) {
  unsigned r;
  asm("v_cvt_pk_bf16_f32 %0, %1, %2" : "=v"(r) : "v"(lo), "v"(hi));
  return r;
}

// ================= f32 -> bf16 convert (x) =================
__global__ __launch_bounds__(256) void conv_bf16(const float* __restrict__ in,
                                                 bf16* __restrict__ out, int n8)
{
  int i = blockIdx.x * blockDim.x + threadIdx.x;
  if (i >= n8) return;
  const float* f = in + (size_t)i * 8;
  float4 a = *(const float4*)f;
  float4 b = *(const float4*)(f + 4);
  union { bf16 h[8]; short8 s; } u;
  u.h[0] = __float2bfloat16(a.x); u.h[1] = __float2bfloat16(a.y);
  u.h[2] = __float2bfloat16(a.z); u.h[3] = __float2bfloat16(a.w);
  u.h[4] = __float2bfloat16(b.x); u.h[5] = __float2bfloat16(b.y);
  u.h[6] = __float2bfloat16(b.z); u.h[7] = __float2bfloat16(b.w);
  *(short8*)(out + (size_t)i * 8) = u.s;
}

// ================= f32 [K][N] -> bf16 transposed [N][ldt] =================
__global__ __launch_bounds__(256) void transpose_conv(const float* __restrict__ W,
                                                      bf16* __restrict__ Wt,
                                                      int N, int ldt)
{
  __shared__ bf16 t[64][72];
  const int tid = threadIdx.x;
  const int n0 = blockIdx.x * 64;
  const int k0 = blockIdx.y * 64;
#pragma unroll
  for (int pass = 0; pass < 4; ++pass) {
    int r = pass * 16 + (tid >> 4);
    int c = (tid & 15) * 4;
    float4 v = *(const float4*)(W + (size_t)(k0 + r) * N + n0 + c);
    t[c + 0][r] = __float2bfloat16(v.x);
    t[c + 1][r] = __float2bfloat16(v.y);
    t[c + 2][r] = __float2bfloat16(v.z);
    t[c + 3][r] = __float2bfloat16(v.w);
  }
  __syncthreads();
#pragma unroll
  for (int pass = 0; pass < 2; ++pass) {
    int n = pass * 32 + (tid >> 3);
    int k8 = (tid & 7) * 8;
    *(short8*)(Wt + (size_t)(n0 + n) * ldt + k0 + k8) = *(const short8*)(&t[n][k8]);
  }
}

// ================= bf16 V region [key][512] -> VT [512][2048] =================
__global__ __launch_bounds__(256) void transpose_v(const bf16* __restrict__ QKV,
                                                   bf16* __restrict__ VT)
{
  __shared__ bf16 t[64][72];
  const int tid = threadIdx.x;
  const int k0 = blockIdx.x * 64;  // keys
  const int d0 = blockIdx.y * 64;  // v-dims (0..511)
#pragma unroll
  for (int pass = 0; pass < 2; ++pass) {
    int c = pass * 256 + tid;
    int r = c >> 3, cq = (c & 7) * 8;
    short8 v = *(const short8*)(QKV + (size_t)(k0 + r) * 3072 + 2560 + d0 + cq);
#pragma unroll
    for (int j = 0; j < 8; ++j) t[cq + j][r] = ((const bf16*)&v)[j];
  }
  __syncthreads();
#pragma unroll
  for (int pass = 0; pass < 2; ++pass) {
    int c = pass * 256 + tid;
    int d = c >> 3, kq = (c & 7) * 8;
    *(short8*)(VT + (size_t)(d0 + d) * 2048 + k0 + kq) = *(const short8*)(&t[d][kq]);
  }
}

// ================= GEMM: C = A(MxK) @ Bt(NxK)^T =================
template <int CF32>
__global__ __launch_bounds__(256) void gemm_bt(const bf16* __restrict__ A,
                                               const bf16* __restrict__ Bt,
                                               void* __restrict__ C,
                                               int M, int N, int K)
{
  __shared__ __align__(16) bf16 As[128 * 32];
  __shared__ __align__(16) bf16 Bs[128 * 32];

  const int tid  = threadIdx.x;
  const int lane = tid & 63;
  const int w    = tid >> 6;
  const int wm   = (w >> 1) * 64;
  const int wn   = (w & 1) * 64;
  const int l15  = lane & 15;
  const int lhi  = lane >> 4;
  const int bm0  = blockIdx.y * 128;
  const int bn0  = blockIdx.x * 128;

  f32x4 acc[4][4];
  const f32x4 zero4 = {0.f, 0.f, 0.f, 0.f};
#pragma unroll
  for (int i = 0; i < 4; ++i)
#pragma unroll
    for (int j = 0; j < 4; ++j) acc[i][j] = zero4;

  for (int k0 = 0; k0 < K; k0 += 32) {
#pragma unroll
    for (int p = 0; p < 2; ++p) {
      int flat16 = (p * 4 + w) * 64 + lane;
      int row = flat16 >> 2;
      int col = (flat16 & 3) * 8;
      GLOAD_LDS16(A  + (size_t)(bm0 + row) * K + k0 + col, As + flat16 * 8);
      GLOAD_LDS16(Bt + (size_t)(bn0 + row) * K + k0 + col, Bs + flat16 * 8);
    }
    __syncthreads();

    short8 a[4], b[4];
#pragma unroll
    for (int mt = 0; mt < 4; ++mt)
      a[mt] = *(const short8*)(As + (wm + mt * 16 + l15) * 32 + lhi * 8);
#pragma unroll
    for (int nt = 0; nt < 4; ++nt)
      b[nt] = *(const short8*)(Bs + (wn + nt * 16 + l15) * 32 + lhi * 8);
#pragma unroll
    for (int mt = 0; mt < 4; ++mt)
#pragma unroll
      for (int nt = 0; nt < 4; ++nt)
        acc[mt][nt] = MFMA16(a[mt], b[nt], acc[mt][nt]);
    __syncthreads();
  }

#pragma unroll
  for (int mt = 0; mt < 4; ++mt) {
    int row0 = bm0 + wm + mt * 16 + lhi * 4;
#pragma unroll
    for (int nt = 0; nt < 4; ++nt) {
      int col = bn0 + wn + nt * 16 + l15;
#pragma unroll
      for (int r = 0; r < 4; ++r) {
        float val = acc[mt][nt][r];
        size_t idx = (size_t)(row0 + r) * N + col;
        if (CF32) ((float*)C)[idx] = val;
        else ((bf16*)C)[idx] = __float2bfloat16(val);
      }
    }
  }
}

// ================= RoPE (in-place, vectorized; Q scaled by 0.125) =================
__global__ __launch_bounds__(256) void rope2(bf16* __restrict__ QKV)
{
  const int NQ = 2048 * 16 * 8;   // (s, h, d8) for Q
  int i = blockIdx.x * blockDim.x + threadIdx.x;
  bf16* base;
  int s, d0;
  float scale;
  if (i < NQ) {
    s = i >> 7;
    int rem = i & 127;
    int h = rem >> 3;
    d0 = (rem & 7) * 8;
    base = QKV + (size_t)s * 3072 + h * 128 + d0;
    scale = 0.125f;
  } else {
    int j = i - NQ;
    if (j >= 2048 * 4 * 8) return;
    s = j >> 5;
    int rem = j & 31;
    int h = rem >> 3;
    d0 = (rem & 7) * 8;
    base = QKV + (size_t)s * 3072 + 2048 + h * 128 + d0;
    scale = 1.f;
  }
  short8 x1v = *(const short8*)base;
  short8 x2v = *(const short8*)(base + 64);
  union { bf16 h[8]; short8 v; } o1, o2;
#pragma unroll
  for (int e = 0; e < 8; ++e) {
    float inv = __expf(-(float)(d0 + e) * (9.210340371976184f / 64.0f));
    float ang = (float)s * inv;
    float c = __cosf(ang), sn = __sinf(ang);
    union { short s; bf16 b; } u1, u2;
    u1.s = x1v[e]; u2.s = x2v[e];
    float x1 = __bfloat162float(u1.b);
    float x2 = __bfloat162float(u2.b);
    o1.h[e] = __float2bfloat16((x1 * c - x2 * sn) * scale);
    o2.h[e] = __float2bfloat16((x2 * c + x1 * sn) * scale);
  }
  *(short8*)base = o1.v;
  *(short8*)(base + 64) = o2.v;
}

// ================= Differential sliding-window attention (swapped-QK) =================
// QKV: [2048][3072] (Q scaled 0.125, roped; K roped). VT: [512][2048]. O: [2048][2048].
__global__ __launch_bounds__(256) void diff_attn(const bf16* __restrict__ QKV,
                                                 const bf16* __restrict__ VT,
                                                 const float* __restrict__ lam,
                                                 bf16* __restrict__ O)
{
  // K tile: 64 keys x 128 dims (16 chunks/row), XOR-swizzled chunks.
  // V tile: 128 dims x 64 keys (8 chunks/row), XOR-swizzled chunks.
  __shared__ __align__(16) bf16 Kb[2][64 * 128];
  __shared__ __align__(16) bf16 Vb[2][128 * 64];
  __shared__ __align__(16) bf16 Pw[4][16 * 72];

  const int qb   = blockIdx.x;
  const int h    = blockIdx.y;
  const int kvh  = h >> 2;
  const int tid  = threadIdx.x;
  const int lane = tid & 63;
  const int w    = tid >> 6;
  const int l15  = lane & 15;
  const int lhi  = lane >> 4;
  const int qg   = qb * 64 + w * 16;
  const int myq  = qg + l15;           // swapped orientation: lane owns q = l15
  const float lamv = lam[h];

  const bf16* Kg = QKV + 2048 + (size_t)kvh * 128;
  const bf16* Vg = VT + (size_t)kvh * 128 * 2048;

  // Q fragments (B-operand: lane l15 = q, elems = dims lhi*8..)
  short8 qf[4];
  {
    const bf16* qrow = QKV + (size_t)myq * 3072 + h * 128;
#pragma unroll
    for (int c = 0; c < 4; ++c)
      qf[c] = *(const short8*)(qrow + c * 32 + lhi * 8);
  }

  const int t0 = (qb >= 8) ? (qb - 8) : 0;

#define STAGE_K(buf, kbase)                                                     \
  {                                                                             \
    _Pragma("unroll")                                                           \
    for (int p = 0; p < 4; ++p) {                                               \
      int c = p * 256 + tid;                                                    \
      int r = c >> 4, q = c & 15;                                               \
      GLOAD_LDS16(Kg + (size_t)((kbase) + r) * 3072 + ((q ^ (r & 7)) * 8),      \
                  &Kb[buf][c * 8]);                                             \
    }                                                                           \
  }
#define STAGE_V(buf, kbase)                                                     \
  {                                                                             \
    _Pragma("unroll")                                                           \
    for (int p = 0; p < 4; ++p) {                                               \
      int c = p * 256 + tid;                                                    \
      int d = c >> 3, q = c & 7;                                                \
      GLOAD_LDS16(Vg + (size_t)d * 2048 + (kbase) + ((q ^ (d & 7)) * 8),        \
                  &Vb[buf][c * 8]);                                             \
    }                                                                           \
  }
  // K A-frag: row = nt*16+l15 (key), dim-chunk qc
#define KFRAG(buf, nt, qc) \
  (*(const short8*)(&Kb[buf][(((nt) * 16 + l15) * 16 + ((qc) ^ (((nt) * 16 + l15) & 7))) * 8]))
  // V B-frag: row = n*16+l15 (dim), key-chunk qc
#define VFRAG(buf, n, qc) \
  (*(const short8*)(&Vb[buf][(((n) * 16 + l15) * 8 + ((qc) ^ (((n) * 16 + l15) & 7))) * 8]))

  const f32x4 zero4 = {0.f, 0.f, 0.f, 0.f};

  // ---------- pass 1: per-lane online softmax stats (no shuffles in loop) ----------
  float m1 = -1e30f, l1 = 0.f, m2 = -1e30f, l2 = 0.f;
  STAGE_K(0, t0 * 64);
  __syncthreads();
  {
    int cur = 0;
    for (int t = t0; t <= qb; ++t, cur ^= 1) {
      if (t < qb) STAGE_K(cur ^ 1, (t + 1) * 64);
      const int kb0 = t * 64;
#pragma unroll
      for (int nt = 0; nt < 4; ++nt) {
        f32x4 s1 = zero4, s2 = zero4;
        s1 = MFMA16(KFRAG(cur, nt, lhi),      qf[0], s1);
        s1 = MFMA16(KFRAG(cur, nt, 4 + lhi),  qf[1], s1);
        s2 = MFMA16(KFRAG(cur, nt, 8 + lhi),  qf[2], s2);
        s2 = MFMA16(KFRAG(cur, nt, 12 + lhi), qf[3], s2);
        const int keyb = kb0 + nt * 16 + lhi * 4;
#pragma unroll
        for (int r = 0; r < 4; ++r) {
          const int key = keyb + r;
          const bool ok = (key <= myq) && (key > myq - 512);
          float v1 = ok ? s1[r] : -1e30f;
          float v2 = ok ? s2[r] : -1e30f;
          float nm1 = fmaxf(m1, v1);
          l1 = l1 * __expf(m1 - nm1) + (ok ? __expf(v1 - nm1) : 0.f);
          m1 = nm1;
          float nm2 = fmaxf(m2, v2);
          l2 = l2 * __expf(m2 - nm2) + (ok ? __expf(v2 - nm2) : 0.f);
          m2 = nm2;
        }
      }
      __syncthreads();
    }
  }

  // combine (m,l) across the 4 lhi lanes (xor 16, 32)
#pragma unroll
  for (int mk = 16; mk <= 32; mk <<= 1) {
    float pm = __shfl_xor(m1, mk, 64), pl = __shfl_xor(l1, mk, 64);
    float M = fmaxf(m1, pm);
    l1 = l1 * __expf(m1 - M) + pl * __expf(pm - M);
    m1 = M;
    pm = __shfl_xor(m2, mk, 64); pl = __shfl_xor(l2, mk, 64);
    M = fmaxf(m2, pm);
    l2 = l2 * __expf(m2 - M) + pl * __expf(pm - M);
    m2 = M;
  }
  const float c2 = lamv * l1 / l2;   // unnormalized-p coefficient

  // ---------- pass 2: p' = relu(e1 - c2*e2), PV accumulate ----------
  f32x4 accv[8];
#pragma unroll
  for (int n = 0; n < 8; ++n) accv[n] = zero4;
  float dln = 0.f;

  STAGE_K(0, t0 * 64);
  STAGE_V(0, t0 * 64);
  __syncthreads();
  {
    int cur = 0;
    for (int t = t0; t <= qb; ++t, cur ^= 1) {
      if (t < qb) {
        STAGE_K(cur ^ 1, (t + 1) * 64);
        STAGE_V(cur ^ 1, (t + 1) * 64);
      }
      const int kb0 = t * 64;
      unsigned* pw = (unsigned*)&Pw[w][0];
#pragma unroll
      for (int nt = 0; nt < 4; ++nt) {
        f32x4 s1 = zero4, s2 = zero4;
        s1 = MFMA16(KFRAG(cur, nt, lhi),      qf[0], s1);
        s1 = MFMA16(KFRAG(cur, nt, 4 + lhi),  qf[1], s1);
        s2 = MFMA16(KFRAG(cur, nt, 8 + lhi),  qf[2], s2);
        s2 = MFMA16(KFRAG(cur, nt, 12 + lhi), qf[3], s2);
        const int keyb = kb0 + nt * 16 + lhi * 4;
        float pr[4];
#pragma unroll
        for (int r = 0; r < 4; ++r) {
          const int key = keyb + r;
          const bool ok = (key <= myq) && (key > myq - 512);
          float e1 = ok ? __expf(s1[r] - m1) : 0.f;
          float e2 = ok ? __expf(s2[r] - m2) : 0.f;
          float p = e1 - c2 * e2;
          pr[r] = p > 0.f ? p : 0.f;
          dln += pr[r];
        }
        int pi = l15 * 36 + 8 * nt + 2 * lhi;
        pw[pi]     = packbf2(pr[0], pr[1]);
        pw[pi + 1] = packbf2(pr[2], pr[3]);
      }
      // PV: accv += P(16q x 64k) @ V^T(64k x 128d)
#pragma unroll
      for (int kc = 0; kc < 2; ++kc) {
        short8 pa = *(const short8*)(&Pw[w][l15 * 72 + kc * 32 + lhi * 8]);
#pragma unroll
        for (int n = 0; n < 8; ++n)
          accv[n] = MFMA16(pa, VFRAG(cur, n, kc * 4 + lhi), accv[n]);
      }
      __syncthreads();
    }
  }

  // combine den across lhi lanes
  dln += __shfl_xor(dln, 16, 64);
  dln += __shfl_xor(dln, 32, 64);

  // ---------- epilogue: out = accv / (den + l1*1e-6) ----------
#pragma unroll
  for (int r = 0; r < 4; ++r) {
    int srcq = lhi * 4 + r;                 // q-local of this output row
    int src = (lane & 48) | srcq;
    float dq = __shfl(dln, src, 64);
    float lq = __shfl(l1, src, 64);
    float rinv = 1.f / (dq + lq * 1e-6f);
    int qo = qg + srcq;
#pragma unroll
    for (int n = 0; n < 8; ++n) {
      O[(size_t)qo * 2048 + h * 128 + n * 16 + l15] =
          __float2bfloat16(accv[n][r] * rinv);
    }
  }
#undef STAGE_K
#undef STAGE_V
#undef KFRAG
#undef VFRAG
}

// ================= launch =================
extern "C" void kernel_launch(void* const* d_in, const int* in_sizes, int n_in,
                              void* d_out, int out_size, void* d_ws, size_t ws_size,
                              hipStream_t stream)
{
  const float* x   = (const float*)d_in[0];
  const float* Wq  = (const float*)d_in[1];
  const float* Wk  = (const float*)d_in[2];
  const float* Wv  = (const float*)d_in[3];
  const float* Wo  = (const float*)d_in[4];
  const float* lam = (const float*)d_in[5];

  char* ws = (char*)d_ws;
  bf16* xb    = (bf16*)(ws);                       // [2048][2048]  8 MB
  bf16* Wqkvt = (bf16*)(ws + 8ull  * (1u << 20));  // [3072][2048] 12 MB
  bf16* Wot   = (bf16*)(ws + 20ull * (1u << 20));  // [2048][2048]  8 MB
  bf16* QKV   = (bf16*)(ws + 28ull * (1u << 20));  // [2048][3072] 12 MB
  bf16* ATT   = (bf16*)(ws + 40ull * (1u << 20));  // [2048][2048]  8 MB
  bf16* VT    = (bf16*)(ws + 48ull * (1u << 20));  // [512][2048]   2 MB (total 50 MB)

  conv_bf16<<<2048, 256, 0, stream>>>(x, xb, 2048 * 2048 / 8);
  transpose_conv<<<dim3(32, 32), 256, 0, stream>>>(Wq, Wqkvt,                2048, 2048);
  transpose_conv<<<dim3(8,  32), 256, 0, stream>>>(Wk, Wqkvt + 2048 * 2048,  512, 2048);
  transpose_conv<<<dim3(8,  32), 256, 0, stream>>>(Wv, Wqkvt + 2560 * 2048,  512, 2048);
  transpose_conv<<<dim3(32, 32), 256, 0, stream>>>(Wo, Wot,                 2048, 2048);

  gemm_bt<0><<<dim3(24, 16), 256, 0, stream>>>(xb, Wqkvt, QKV, 2048, 3072, 2048);
  rope2<<<1280, 256, 0, stream>>>(QKV);
  transpose_v<<<dim3(32, 8), 256, 0, stream>>>(QKV, VT);
  diff_attn<<<dim3(32, 16), 256, 0, stream>>>(QKV, VT, lam, d_out ? (bf16*)ATT : (bf16*)ATT);
  gemm_bt<1><<<dim3(16, 16), 256, 0, stream>>>(ATT, Wot, d_out, 2048, 2048, 2048);
}

// Round 5
// 160.454 us; speedup vs baseline: 4.3637x; 1.1031x over previous
//
#include <hip/hip_runtime.h>
#include <hip/hip_bf16.h>
#include <stdint.h>

typedef __attribute__((ext_vector_type(8))) short short8;
typedef __attribute__((ext_vector_type(4))) float f32x4;
using bf16 = __hip_bfloat16;

#define MFMA16(a, b, c) __builtin_amdgcn_mfma_f32_16x16x32_bf16((a), (b), (c), 0, 0, 0)

#define GLOAD_LDS16(g, l) __builtin_amdgcn_global_load_lds( \
    (const __attribute__((address_space(1))) void*)(g),     \
    (__attribute__((address_space(3))) void*)(l), 16, 0, 0)

__device__ __forceinline__ unsigned packbf2(float lo, float hi) {
  unsigned r;
  asm("v_cvt_pk_bf16_f32 %0, %1, %2" : "=v"(r) : "v"(lo), "v"(hi));
  return r;
}

// ================= fused prep: x f32->bf16 + all weight transpose-converts =================
// grid (144, 32):
//   bx   0..31 : Wq -> Wqkvt[0]        (N=2048)
//   bx  32..39 : Wk -> Wqkvt+2048*2048 (N=512)
//   bx  40..47 : Wv -> Wqkvt+2560*2048 (N=512)
//   bx  48..79 : Wo -> Wot             (N=2048)
//   bx 80..143 : x  -> xb (convert, (bx-80)*32+by block of 2048 elems)
__global__ __launch_bounds__(256) void prep_all(const float* __restrict__ x,
                                                const float* __restrict__ Wq,
                                                const float* __restrict__ Wk,
                                                const float* __restrict__ Wv,
                                                const float* __restrict__ Wo,
                                                bf16* __restrict__ xb,
                                                bf16* __restrict__ Wqkvt,
                                                bf16* __restrict__ Wot)
{
  const int bx = blockIdx.x;
  const int tid = threadIdx.x;
  if (bx >= 80) {
    // convert x
    size_t i = ((size_t)(bx - 80) * 32 + blockIdx.y) * 2048 + tid * 8;
    const float* f = x + i;
    float4 a = *(const float4*)f;
    float4 b = *(const float4*)(f + 4);
    union { bf16 h[8]; short8 s; } u;
    u.h[0] = __float2bfloat16(a.x); u.h[1] = __float2bfloat16(a.y);
    u.h[2] = __float2bfloat16(a.z); u.h[3] = __float2bfloat16(a.w);
    u.h[4] = __float2bfloat16(b.x); u.h[5] = __float2bfloat16(b.y);
    u.h[6] = __float2bfloat16(b.z); u.h[7] = __float2bfloat16(b.w);
    *(short8*)(xb + i) = u.s;
    return;
  }
  const float* W;
  bf16* Wt;
  int N, n0;
  if (bx < 32)      { W = Wq; Wt = Wqkvt;                    N = 2048; n0 = bx * 64; }
  else if (bx < 40) { W = Wk; Wt = Wqkvt + 2048 * 2048;      N = 512;  n0 = (bx - 32) * 64; }
  else if (bx < 48) { W = Wv; Wt = Wqkvt + 2560 * 2048;      N = 512;  n0 = (bx - 40) * 64; }
  else              { W = Wo; Wt = Wot;                      N = 2048; n0 = (bx - 48) * 64; }
  const int k0 = blockIdx.y * 64;

  __shared__ bf16 t[64][72];
#pragma unroll
  for (int pass = 0; pass < 4; ++pass) {
    int r = pass * 16 + (tid >> 4);
    int c = (tid & 15) * 4;
    float4 v = *(const float4*)(W + (size_t)(k0 + r) * N + n0 + c);
    t[c + 0][r] = __float2bfloat16(v.x);
    t[c + 1][r] = __float2bfloat16(v.y);
    t[c + 2][r] = __float2bfloat16(v.z);
    t[c + 3][r] = __float2bfloat16(v.w);
  }
  __syncthreads();
#pragma unroll
  for (int pass = 0; pass < 2; ++pass) {
    int n = pass * 32 + (tid >> 3);
    int k8 = (tid & 7) * 8;
    *(short8*)(Wt + (size_t)(n0 + n) * 2048 + k0 + k8) = *(const short8*)(&t[n][k8]);
  }
}

// ================= bf16 V region [key][512] -> VT [512][2048] =================
__global__ __launch_bounds__(256) void transpose_v(const bf16* __restrict__ QKV,
                                                   bf16* __restrict__ VT)
{
  __shared__ bf16 t[64][72];
  const int tid = threadIdx.x;
  const int k0 = blockIdx.x * 64;
  const int d0 = blockIdx.y * 64;
#pragma unroll
  for (int pass = 0; pass < 2; ++pass) {
    int c = pass * 256 + tid;
    int r = c >> 3, cq = (c & 7) * 8;
    short8 v = *(const short8*)(QKV + (size_t)(k0 + r) * 3072 + 2560 + d0 + cq);
#pragma unroll
    for (int j = 0; j < 8; ++j) t[cq + j][r] = ((const bf16*)&v)[j];
  }
  __syncthreads();
#pragma unroll
  for (int pass = 0; pass < 2; ++pass) {
    int c = pass * 256 + tid;
    int d = c >> 3, kq = (c & 7) * 8;
    *(short8*)(VT + (size_t)(d0 + d) * 2048 + k0 + kq) = *(const short8*)(&t[d][kq]);
  }
}

// ================= GEMM: C = A(MxK) @ Bt(NxK)^T, double-buffered 2-phase =================
template <int CF32>
__global__ __launch_bounds__(256) void gemm_bt(const bf16* __restrict__ A,
                                               const bf16* __restrict__ Bt,
                                               void* __restrict__ C,
                                               int M, int N, int K)
{
  __shared__ __align__(16) bf16 As[2][128 * 32];
  __shared__ __align__(16) bf16 Bs[2][128 * 32];

  const int tid  = threadIdx.x;
  const int lane = tid & 63;
  const int w    = tid >> 6;
  const int wm   = (w >> 1) * 64;
  const int wn   = (w & 1) * 64;
  const int l15  = lane & 15;
  const int lhi  = lane >> 4;
  const int bm0  = blockIdx.y * 128;
  const int bn0  = blockIdx.x * 128;

  f32x4 acc[4][4];
  const f32x4 zero4 = {0.f, 0.f, 0.f, 0.f};
#pragma unroll
  for (int i = 0; i < 4; ++i)
#pragma unroll
    for (int j = 0; j < 4; ++j) acc[i][j] = zero4;

#define GSTAGE(buf, kk)                                                          \
  {                                                                              \
    _Pragma("unroll")                                                            \
    for (int p = 0; p < 2; ++p) {                                                \
      int flat16 = (p * 4 + w) * 64 + lane;                                      \
      int row = flat16 >> 2;                                                     \
      int col = (flat16 & 3) * 8;                                                \
      GLOAD_LDS16(A  + (size_t)(bm0 + row) * K + (kk) + col, &As[buf][flat16 * 8]); \
      GLOAD_LDS16(Bt + (size_t)(bn0 + row) * K + (kk) + col, &Bs[buf][flat16 * 8]); \
    }                                                                            \
  }

  const int nk = K >> 5;
  GSTAGE(0, 0);
  __syncthreads();
  int cur = 0;
  for (int t = 0; t < nk; ++t, cur ^= 1) {
    if (t + 1 < nk) GSTAGE(cur ^ 1, (t + 1) * 32);  // prefetch overlaps this tile's MFMAs
    short8 a[4], b[4];
#pragma unroll
    for (int mt = 0; mt < 4; ++mt)
      a[mt] = *(const short8*)(&As[cur][(wm + mt * 16 + l15) * 32 + lhi * 8]);
#pragma unroll
    for (int nt = 0; nt < 4; ++nt)
      b[nt] = *(const short8*)(&Bs[cur][(wn + nt * 16 + l15) * 32 + lhi * 8]);
#pragma unroll
    for (int mt = 0; mt < 4; ++mt)
#pragma unroll
      for (int nt = 0; nt < 4; ++nt)
        acc[mt][nt] = MFMA16(a[mt], b[nt], acc[mt][nt]);
    __syncthreads();  // drains vmcnt(0)+lgkmcnt: buf[cur^1] staged, buf[cur] reads done
  }
#undef GSTAGE

#pragma unroll
  for (int mt = 0; mt < 4; ++mt) {
    int row0 = bm0 + wm + mt * 16 + lhi * 4;
#pragma unroll
    for (int nt = 0; nt < 4; ++nt) {
      int col = bn0 + wn + nt * 16 + l15;
#pragma unroll
      for (int r = 0; r < 4; ++r) {
        float val = acc[mt][nt][r];
        size_t idx = (size_t)(row0 + r) * N + col;
        if (CF32) ((float*)C)[idx] = val;
        else ((bf16*)C)[idx] = __float2bfloat16(val);
      }
    }
  }
}

// ================= RoPE (in-place, vectorized; Q scaled by 0.125) =================
__global__ __launch_bounds__(256) void rope2(bf16* __restrict__ QKV)
{
  const int NQ = 2048 * 16 * 8;
  int i = blockIdx.x * blockDim.x + threadIdx.x;
  bf16* base;
  int s, d0;
  float scale;
  if (i < NQ) {
    s = i >> 7;
    int rem = i & 127;
    int h = rem >> 3;
    d0 = (rem & 7) * 8;
    base = QKV + (size_t)s * 3072 + h * 128 + d0;
    scale = 0.125f;
  } else {
    int j = i - NQ;
    if (j >= 2048 * 4 * 8) return;
    s = j >> 5;
    int rem = j & 31;
    int h = rem >> 3;
    d0 = (rem & 7) * 8;
    base = QKV + (size_t)s * 3072 + 2048 + h * 128 + d0;
    scale = 1.f;
  }
  short8 x1v = *(const short8*)base;
  short8 x2v = *(const short8*)(base + 64);
  union { bf16 h[8]; short8 v; } o1, o2;
#pragma unroll
  for (int e = 0; e < 8; ++e) {
    float inv = __expf(-(float)(d0 + e) * (9.210340371976184f / 64.0f));
    float ang = (float)s * inv;
    float c = __cosf(ang), sn = __sinf(ang);
    union { short s; bf16 b; } u1, u2;
    u1.s = x1v[e]; u2.s = x2v[e];
    float x1 = __bfloat162float(u1.b);
    float x2 = __bfloat162float(u2.b);
    o1.h[e] = __float2bfloat16((x1 * c - x2 * sn) * scale);
    o2.h[e] = __float2bfloat16((x2 * c + x1 * sn) * scale);
  }
  *(short8*)base = o1.v;
  *(short8*)(base + 64) = o2.v;
}

// ================= Differential sliding-window attention (swapped-QK) =================
__global__ __launch_bounds__(256) void diff_attn(const bf16* __restrict__ QKV,
                                                 const bf16* __restrict__ VT,
                                                 const float* __restrict__ lam,
                                                 bf16* __restrict__ O)
{
  __shared__ __align__(16) bf16 Kb[2][64 * 128];
  __shared__ __align__(16) bf16 Vb[2][128 * 64];
  __shared__ __align__(16) bf16 Pw[4][16 * 72];

  const int qb   = blockIdx.x;
  const int h    = blockIdx.y;
  const int kvh  = h >> 2;
  const int tid  = threadIdx.x;
  const int lane = tid & 63;
  const int w    = tid >> 6;
  const int l15  = lane & 15;
  const int lhi  = lane >> 4;
  const int qg   = qb * 64 + w * 16;
  const int myq  = qg + l15;
  const float lamv = lam[h];

  const bf16* Kg = QKV + 2048 + (size_t)kvh * 128;
  const bf16* Vg = VT + (size_t)kvh * 128 * 2048;

  short8 qf[4];
  {
    const bf16* qrow = QKV + (size_t)myq * 3072 + h * 128;
#pragma unroll
    for (int c = 0; c < 4; ++c)
      qf[c] = *(const short8*)(qrow + c * 32 + lhi * 8);
  }

  const int t0 = (qb >= 8) ? (qb - 8) : 0;

#define STAGE_K(buf, kbase)                                                     \
  {                                                                             \
    _Pragma("unroll")                                                           \
    for (int p = 0; p < 4; ++p) {                                               \
      int c = p * 256 + tid;                                                    \
      int r = c >> 4, q = c & 15;                                               \
      GLOAD_LDS16(Kg + (size_t)((kbase) + r) * 3072 + ((q ^ (r & 7)) * 8),      \
                  &Kb[buf][c * 8]);                                             \
    }                                                                           \
  }
#define STAGE_V(buf, kbase)                                                     \
  {                                                                             \
    _Pragma("unroll")                                                           \
    for (int p = 0; p < 4; ++p) {                                               \
      int c = p * 256 + tid;                                                    \
      int d = c >> 3, q = c & 7;                                                \
      GLOAD_LDS16(Vg + (size_t)d * 2048 + (kbase) + ((q ^ (d & 7)) * 8),        \
                  &Vb[buf][c * 8]);                                             \
    }                                                                           \
  }
#define KFRAG(buf, nt, qc) \
  (*(const short8*)(&Kb[buf][(((nt) * 16 + l15) * 16 + ((qc) ^ (((nt) * 16 + l15) & 7))) * 8]))
#define VFRAG(buf, n, qc) \
  (*(const short8*)(&Vb[buf][(((n) * 16 + l15) * 8 + ((qc) ^ (((n) * 16 + l15) & 7))) * 8]))

  const f32x4 zero4 = {0.f, 0.f, 0.f, 0.f};

  // pass 1: per-lane online softmax stats
  float m1 = -1e30f, l1 = 0.f, m2 = -1e30f, l2 = 0.f;
  STAGE_K(0, t0 * 64);
  __syncthreads();
  {
    int cur = 0;
    for (int t = t0; t <= qb; ++t, cur ^= 1) {
      if (t < qb) STAGE_K(cur ^ 1, (t + 1) * 64);
      const int kb0 = t * 64;
#pragma unroll
      for (int nt = 0; nt < 4; ++nt) {
        f32x4 s1 = zero4, s2 = zero4;
        s1 = MFMA16(KFRAG(cur, nt, lhi),      qf[0], s1);
        s1 = MFMA16(KFRAG(cur, nt, 4 + lhi),  qf[1], s1);
        s2 = MFMA16(KFRAG(cur, nt, 8 + lhi),  qf[2], s2);
        s2 = MFMA16(KFRAG(cur, nt, 12 + lhi), qf[3], s2);
        const int keyb = kb0 + nt * 16 + lhi * 4;
#pragma unroll
        for (int r = 0; r < 4; ++r) {
          const int key = keyb + r;
          const bool ok = (key <= myq) && (key > myq - 512);
          float v1 = ok ? s1[r] : -1e30f;
          float v2 = ok ? s2[r] : -1e30f;
          float nm1 = fmaxf(m1, v1);
          l1 = l1 * __expf(m1 - nm1) + (ok ? __expf(v1 - nm1) : 0.f);
          m1 = nm1;
          float nm2 = fmaxf(m2, v2);
          l2 = l2 * __expf(m2 - nm2) + (ok ? __expf(v2 - nm2) : 0.f);
          m2 = nm2;
        }
      }
      __syncthreads();
    }
  }

#pragma unroll
  for (int mk = 16; mk <= 32; mk <<= 1) {
    float pm = __shfl_xor(m1, mk, 64), pl = __shfl_xor(l1, mk, 64);
    float M = fmaxf(m1, pm);
    l1 = l1 * __expf(m1 - M) + pl * __expf(pm - M);
    m1 = M;
    pm = __shfl_xor(m2, mk, 64); pl = __shfl_xor(l2, mk, 64);
    M = fmaxf(m2, pm);
    l2 = l2 * __expf(m2 - M) + pl * __expf(pm - M);
    m2 = M;
  }
  const float c2 = lamv * l1 / l2;

  // pass 2: p' = relu(e1 - c2*e2), PV accumulate
  f32x4 accv[8];
#pragma unroll
  for (int n = 0; n < 8; ++n) accv[n] = zero4;
  float dln = 0.f;

  STAGE_K(0, t0 * 64);
  STAGE_V(0, t0 * 64);
  __syncthreads();
  {
    int cur = 0;
    for (int t = t0; t <= qb; ++t, cur ^= 1) {
      if (t < qb) {
        STAGE_K(cur ^ 1, (t + 1) * 64);
        STAGE_V(cur ^ 1, (t + 1) * 64);
      }
      const int kb0 = t * 64;
      unsigned* pw = (unsigned*)&Pw[w][0];
#pragma unroll
      for (int nt = 0; nt < 4; ++nt) {
        f32x4 s1 = zero4, s2 = zero4;
        s1 = MFMA16(KFRAG(cur, nt, lhi),      qf[0], s1);
        s1 = MFMA16(KFRAG(cur, nt, 4 + lhi),  qf[1], s1);
        s2 = MFMA16(KFRAG(cur, nt, 8 + lhi),  qf[2], s2);
        s2 = MFMA16(KFRAG(cur, nt, 12 + lhi), qf[3], s2);
        const int keyb = kb0 + nt * 16 + lhi * 4;
        float pr[4];
#pragma unroll
        for (int r = 0; r < 4; ++r) {
          const int key = keyb + r;
          const bool ok = (key <= myq) && (key > myq - 512);
          float e1 = ok ? __expf(s1[r] - m1) : 0.f;
          float e2 = ok ? __expf(s2[r] - m2) : 0.f;
          float p = e1 - c2 * e2;
          pr[r] = p > 0.f ? p : 0.f;
          dln += pr[r];
        }
        int pi = l15 * 36 + 8 * nt + 2 * lhi;
        pw[pi]     = packbf2(pr[0], pr[1]);
        pw[pi + 1] = packbf2(pr[2], pr[3]);
      }
#pragma unroll
      for (int kc = 0; kc < 2; ++kc) {
        short8 pa = *(const short8*)(&Pw[w][l15 * 72 + kc * 32 + lhi * 8]);
#pragma unroll
        for (int n = 0; n < 8; ++n)
          accv[n] = MFMA16(pa, VFRAG(cur, n, kc * 4 + lhi), accv[n]);
      }
      __syncthreads();
    }
  }

  dln += __shfl_xor(dln, 16, 64);
  dln += __shfl_xor(dln, 32, 64);

#pragma unroll
  for (int r = 0; r < 4; ++r) {
    int srcq = lhi * 4 + r;
    int src = (lane & 48) | srcq;
    float dq = __shfl(dln, src, 64);
    float lq = __shfl(l1, src, 64);
    float rinv = 1.f / (dq + lq * 1e-6f);
    int qo = qg + srcq;
#pragma unroll
    for (int n = 0; n < 8; ++n) {
      O[(size_t)qo * 2048 + h * 128 + n * 16 + l15] =
          __float2bfloat16(accv[n][r] * rinv);
    }
  }
#undef STAGE_K
#undef STAGE_V
#undef KFRAG
#undef VFRAG
}

// ================= launch =================
extern "C" void kernel_launch(void* const* d_in, const int* in_sizes, int n_in,
                              void* d_out, int out_size, void* d_ws, size_t ws_size,
                              hipStream_t stream)
{
  const float* x   = (const float*)d_in[0];
  const float* Wq  = (const float*)d_in[1];
  const float* Wk  = (const float*)d_in[2];
  const float* Wv  = (const float*)d_in[3];
  const float* Wo  = (const float*)d_in[4];
  const float* lam = (const float*)d_in[5];

  char* ws = (char*)d_ws;
  bf16* xb    = (bf16*)(ws);                       // [2048][2048]  8 MB
  bf16* Wqkvt = (bf16*)(ws + 8ull  * (1u << 20));  // [3072][2048] 12 MB
  bf16* Wot   = (bf16*)(ws + 20ull * (1u << 20));  // [2048][2048]  8 MB
  bf16* QKV   = (bf16*)(ws + 28ull * (1u << 20));  // [2048][3072] 12 MB
  bf16* ATT   = (bf16*)(ws + 40ull * (1u << 20));  // [2048][2048]  8 MB
  bf16* VT    = (bf16*)(ws + 48ull * (1u << 20));  // [512][2048]   2 MB

  prep_all<<<dim3(144, 32), 256, 0, stream>>>(x, Wq, Wk, Wv, Wo, xb, Wqkvt, Wot);
  gemm_bt<0><<<dim3(24, 16), 256, 0, stream>>>(xb, Wqkvt, QKV, 2048, 3072, 2048);
  rope2<<<1280, 256, 0, stream>>>(QKV);
  transpose_v<<<dim3(32, 8), 256, 0, stream>>>(QKV, VT);
  diff_attn<<<dim3(32, 16), 256, 0, stream>>>(QKV, VT, lam, ATT);
  gemm_bt<1><<<dim3(16, 16), 256, 0, stream>>>(ATT, Wot, d_out, 2048, 2048, 2048);
}

// Round 6
// 158.171 us; speedup vs baseline: 4.4267x; 1.0144x over previous
//
#include <hip/hip_runtime.h>
#include <hip/hip_bf16.h>
#include <stdint.h>

typedef __attribute__((ext_vector_type(8))) short short8;
typedef __attribute__((ext_vector_type(4))) float f32x4;
using bf16 = __hip_bfloat16;

#define MFMA16(a, b, c) __builtin_amdgcn_mfma_f32_16x16x32_bf16((a), (b), (c), 0, 0, 0)

#define GLOAD_LDS16(g, l) __builtin_amdgcn_global_load_lds( \
    (const __attribute__((address_space(1))) void*)(g),     \
    (__attribute__((address_space(3))) void*)(l), 16, 0, 0)

__device__ __forceinline__ unsigned packbf2(float lo, float hi) {
  unsigned r;
  asm("v_cvt_pk_bf16_f32 %0, %1, %2" : "=v"(r) : "v"(lo), "v"(hi));
  return r;
}

// ================= fused prep: x f32->bf16 + all weight transpose-converts =================
__global__ __launch_bounds__(256) void prep_all(const float* __restrict__ x,
                                                const float* __restrict__ Wq,
                                                const float* __restrict__ Wk,
                                                const float* __restrict__ Wv,
                                                const float* __restrict__ Wo,
                                                bf16* __restrict__ xb,
                                                bf16* __restrict__ Wqkvt,
                                                bf16* __restrict__ Wot)
{
  const int bx = blockIdx.x;
  const int tid = threadIdx.x;
  if (bx >= 80) {
    size_t i = ((size_t)(bx - 80) * 32 + blockIdx.y) * 2048 + tid * 8;
    const float* f = x + i;
    float4 a = *(const float4*)f;
    float4 b = *(const float4*)(f + 4);
    union { bf16 h[8]; short8 s; } u;
    u.h[0] = __float2bfloat16(a.x); u.h[1] = __float2bfloat16(a.y);
    u.h[2] = __float2bfloat16(a.z); u.h[3] = __float2bfloat16(a.w);
    u.h[4] = __float2bfloat16(b.x); u.h[5] = __float2bfloat16(b.y);
    u.h[6] = __float2bfloat16(b.z); u.h[7] = __float2bfloat16(b.w);
    *(short8*)(xb + i) = u.s;
    return;
  }
  const float* W;
  bf16* Wt;
  int N, n0;
  if (bx < 32)      { W = Wq; Wt = Wqkvt;                    N = 2048; n0 = bx * 64; }
  else if (bx < 40) { W = Wk; Wt = Wqkvt + 2048 * 2048;      N = 512;  n0 = (bx - 32) * 64; }
  else if (bx < 48) { W = Wv; Wt = Wqkvt + 2560 * 2048;      N = 512;  n0 = (bx - 40) * 64; }
  else              { W = Wo; Wt = Wot;                      N = 2048; n0 = (bx - 48) * 64; }
  const int k0 = blockIdx.y * 64;

  __shared__ bf16 t[64][72];
#pragma unroll
  for (int pass = 0; pass < 4; ++pass) {
    int r = pass * 16 + (tid >> 4);
    int c = (tid & 15) * 4;
    float4 v = *(const float4*)(W + (size_t)(k0 + r) * N + n0 + c);
    t[c + 0][r] = __float2bfloat16(v.x);
    t[c + 1][r] = __float2bfloat16(v.y);
    t[c + 2][r] = __float2bfloat16(v.z);
    t[c + 3][r] = __float2bfloat16(v.w);
  }
  __syncthreads();
#pragma unroll
  for (int pass = 0; pass < 2; ++pass) {
    int n = pass * 32 + (tid >> 3);
    int k8 = (tid & 7) * 8;
    *(short8*)(Wt + (size_t)(n0 + n) * 2048 + k0 + k8) = *(const short8*)(&t[n][k8]);
  }
}

// ================= bf16 V region [key][512] -> VT [512][2048] =================
__global__ __launch_bounds__(256) void transpose_v(const bf16* __restrict__ QKV,
                                                   bf16* __restrict__ VT)
{
  __shared__ bf16 t[64][72];
  const int tid = threadIdx.x;
  const int k0 = blockIdx.x * 64;
  const int d0 = blockIdx.y * 64;
#pragma unroll
  for (int pass = 0; pass < 2; ++pass) {
    int c = pass * 256 + tid;
    int r = c >> 3, cq = (c & 7) * 8;
    short8 v = *(const short8*)(QKV + (size_t)(k0 + r) * 3072 + 2560 + d0 + cq);
#pragma unroll
    for (int j = 0; j < 8; ++j) t[cq + j][r] = ((const bf16*)&v)[j];
  }
  __syncthreads();
#pragma unroll
  for (int pass = 0; pass < 2; ++pass) {
    int c = pass * 256 + tid;
    int d = c >> 3, kq = (c & 7) * 8;
    *(short8*)(VT + (size_t)(d0 + d) * 2048 + k0 + kq) = *(const short8*)(&t[d][kq]);
  }
}

// ================= GEMM: C = A(MxK) @ Bt(NxK)^T, 4-deep counted-vmcnt pipeline =================
// Each K-step stage = 4 global_load_lds per thread (2 A + 2 B).
// Loop: wait vmcnt(8) [2 stages in flight] -> s_barrier -> issue stage t+3 -> compute t.
template <int CF32>
__global__ __launch_bounds__(256) void gemm_bt(const bf16* __restrict__ A,
                                               const bf16* __restrict__ Bt,
                                               void* __restrict__ C,
                                               int M, int N, int K)
{
  __shared__ __align__(16) bf16 As[4][128 * 32];
  __shared__ __align__(16) bf16 Bs[4][128 * 32];

  const int tid  = threadIdx.x;
  const int lane = tid & 63;
  const int w    = tid >> 6;
  const int wm   = (w >> 1) * 64;
  const int wn   = (w & 1) * 64;
  const int l15  = lane & 15;
  const int lhi  = lane >> 4;
  const int bm0  = blockIdx.y * 128;
  const int bn0  = blockIdx.x * 128;

  f32x4 acc[4][4];
  const f32x4 zero4 = {0.f, 0.f, 0.f, 0.f};
#pragma unroll
  for (int i = 0; i < 4; ++i)
#pragma unroll
    for (int j = 0; j < 4; ++j) acc[i][j] = zero4;

#define GSTAGE(buf, kk)                                                             \
  {                                                                                 \
    _Pragma("unroll")                                                               \
    for (int p = 0; p < 2; ++p) {                                                   \
      int flat16 = (p * 4 + w) * 64 + lane;                                         \
      int row = flat16 >> 2;                                                        \
      int col = (flat16 & 3) * 8;                                                   \
      GLOAD_LDS16(A  + (size_t)(bm0 + row) * K + (kk) + col, &As[buf][flat16 * 8]); \
      GLOAD_LDS16(Bt + (size_t)(bn0 + row) * K + (kk) + col, &Bs[buf][flat16 * 8]); \
    }                                                                               \
  }

  const int nk = K >> 5;  // >= 4 always here (K = 2048)
  GSTAGE(0, 0);
  GSTAGE(1, 32);
  GSTAGE(2, 64);

  auto kstep = [&](int t, int wc) {
    // wait for the tile we're about to consume; keep later stages in flight
    if (wc == 8)      asm volatile("s_waitcnt vmcnt(8)" ::: "memory");
    else if (wc == 4) asm volatile("s_waitcnt vmcnt(4)" ::: "memory");
    else              asm volatile("s_waitcnt vmcnt(0)" ::: "memory");
    __builtin_amdgcn_s_barrier();
    __builtin_amdgcn_sched_barrier(0);
    if (t + 3 < nk) GSTAGE((t + 3) & 3, (t + 3) * 32);
    const int cur = t & 3;
    short8 a[4], b[4];
#pragma unroll
    for (int mt = 0; mt < 4; ++mt)
      a[mt] = *(const short8*)(&As[cur][(wm + mt * 16 + l15) * 32 + lhi * 8]);
#pragma unroll
    for (int nt = 0; nt < 4; ++nt)
      b[nt] = *(const short8*)(&Bs[cur][(wn + nt * 16 + l15) * 32 + lhi * 8]);
#pragma unroll
    for (int mt = 0; mt < 4; ++mt)
#pragma unroll
      for (int nt = 0; nt < 4; ++nt)
        acc[mt][nt] = MFMA16(a[mt], b[nt], acc[mt][nt]);
  };

  for (int t = 0; t < nk - 2; ++t) kstep(t, 8);
  kstep(nk - 2, 4);
  kstep(nk - 1, 0);
#undef GSTAGE

#pragma unroll
  for (int mt = 0; mt < 4; ++mt) {
    int row0 = bm0 + wm + mt * 16 + lhi * 4;
#pragma unroll
    for (int nt = 0; nt < 4; ++nt) {
      int col = bn0 + wn + nt * 16 + l15;
#pragma unroll
      for (int r = 0; r < 4; ++r) {
        float val = acc[mt][nt][r];
        size_t idx = (size_t)(row0 + r) * N + col;
        if (CF32) ((float*)C)[idx] = val;
        else ((bf16*)C)[idx] = __float2bfloat16(val);
      }
    }
  }
}

// ================= RoPE (in-place, vectorized; Q scaled by 0.125) =================
__global__ __launch_bounds__(256) void rope2(bf16* __restrict__ QKV)
{
  const int NQ = 2048 * 16 * 8;
  int i = blockIdx.x * blockDim.x + threadIdx.x;
  bf16* base;
  int s, d0;
  float scale;
  if (i < NQ) {
    s = i >> 7;
    int rem = i & 127;
    int h = rem >> 3;
    d0 = (rem & 7) * 8;
    base = QKV + (size_t)s * 3072 + h * 128 + d0;
    scale = 0.125f;
  } else {
    int j = i - NQ;
    if (j >= 2048 * 4 * 8) return;
    s = j >> 5;
    int rem = j & 31;
    int h = rem >> 3;
    d0 = (rem & 7) * 8;
    base = QKV + (size_t)s * 3072 + 2048 + h * 128 + d0;
    scale = 1.f;
  }
  short8 x1v = *(const short8*)base;
  short8 x2v = *(const short8*)(base + 64);
  union { bf16 h[8]; short8 v; } o1, o2;
#pragma unroll
  for (int e = 0; e < 8; ++e) {
    float inv = __expf(-(float)(d0 + e) * (9.210340371976184f / 64.0f));
    float ang = (float)s * inv;
    float c = __cosf(ang), sn = __sinf(ang);
    union { short s; bf16 b; } u1, u2;
    u1.s = x1v[e]; u2.s = x2v[e];
    float x1 = __bfloat162float(u1.b);
    float x2 = __bfloat162float(u2.b);
    o1.h[e] = __float2bfloat16((x1 * c - x2 * sn) * scale);
    o2.h[e] = __float2bfloat16((x2 * c + x1 * sn) * scale);
  }
  *(short8*)base = o1.v;
  *(short8*)(base + 64) = o2.v;
}

// ================= Differential sliding-window attention (swapped-QK) =================
__global__ __launch_bounds__(256) void diff_attn(const bf16* __restrict__ QKV,
                                                 const bf16* __restrict__ VT,
                                                 const float* __restrict__ lam,
                                                 bf16* __restrict__ O)
{
  __shared__ __align__(16) bf16 Kb[2][64 * 128];
  __shared__ __align__(16) bf16 Vb[2][128 * 64];
  __shared__ __align__(16) bf16 Pw[4][16 * 72];

  const int qb   = blockIdx.x;
  const int h    = blockIdx.y;
  const int kvh  = h >> 2;
  const int tid  = threadIdx.x;
  const int lane = tid & 63;
  const int w    = tid >> 6;
  const int l15  = lane & 15;
  const int lhi  = lane >> 4;
  const int qg   = qb * 64 + w * 16;
  const int myq  = qg + l15;
  const float lamv = lam[h];

  const bf16* Kg = QKV + 2048 + (size_t)kvh * 128;
  const bf16* Vg = VT + (size_t)kvh * 128 * 2048;

  short8 qf[4];
  {
    const bf16* qrow = QKV + (size_t)myq * 3072 + h * 128;
#pragma unroll
    for (int c = 0; c < 4; ++c)
      qf[c] = *(const short8*)(qrow + c * 32 + lhi * 8);
  }

  const int t0 = (qb >= 8) ? (qb - 8) : 0;

#define STAGE_K(buf, kbase)                                                     \
  {                                                                             \
    _Pragma("unroll")                                                           \
    for (int p = 0; p < 4; ++p) {                                               \
      int c = p * 256 + tid;                                                    \
      int r = c >> 4, q = c & 15;                                               \
      GLOAD_LDS16(Kg + (size_t)((kbase) + r) * 3072 + ((q ^ (r & 7)) * 8),      \
                  &Kb[buf][c * 8]);                                             \
    }                                                                           \
  }
#define STAGE_V(buf, kbase)                                                     \
  {                                                                             \
    _Pragma("unroll")                                                           \
    for (int p = 0; p < 4; ++p) {                                               \
      int c = p * 256 + tid;                                                    \
      int d = c >> 3, q = c & 7;                                                \
      GLOAD_LDS16(Vg + (size_t)d * 2048 + (kbase) + ((q ^ (d & 7)) * 8),        \
                  &Vb[buf][c * 8]);                                             \
    }                                                                           \
  }
#define KFRAG(buf, nt, qc) \
  (*(const short8*)(&Kb[buf][(((nt) * 16 + l15) * 16 + ((qc) ^ (((nt) * 16 + l15) & 7))) * 8]))
#define VFRAG(buf, n, qc) \
  (*(const short8*)(&Vb[buf][(((n) * 16 + l15) * 8 + ((qc) ^ (((n) * 16 + l15) & 7))) * 8]))

  const f32x4 zero4 = {0.f, 0.f, 0.f, 0.f};

  // pass 1: per-lane online softmax stats
  float m1 = -1e30f, l1 = 0.f, m2 = -1e30f, l2 = 0.f;
  STAGE_K(0, t0 * 64);
  __syncthreads();
  {
    int cur = 0;
    for (int t = t0; t <= qb; ++t, cur ^= 1) {
      if (t < qb) STAGE_K(cur ^ 1, (t + 1) * 64);
      const int kb0 = t * 64;
#pragma unroll
      for (int nt = 0; nt < 4; ++nt) {
        f32x4 s1 = zero4, s2 = zero4;
        s1 = MFMA16(KFRAG(cur, nt, lhi),      qf[0], s1);
        s1 = MFMA16(KFRAG(cur, nt, 4 + lhi),  qf[1], s1);
        s2 = MFMA16(KFRAG(cur, nt, 8 + lhi),  qf[2], s2);
        s2 = MFMA16(KFRAG(cur, nt, 12 + lhi), qf[3], s2);
        const int keyb = kb0 + nt * 16 + lhi * 4;
#pragma unroll
        for (int r = 0; r < 4; ++r) {
          const int key = keyb + r;
          const bool ok = (key <= myq) && (key > myq - 512);
          float v1 = ok ? s1[r] : -1e30f;
          float v2 = ok ? s2[r] : -1e30f;
          float nm1 = fmaxf(m1, v1);
          l1 = l1 * __expf(m1 - nm1) + (ok ? __expf(v1 - nm1) : 0.f);
          m1 = nm1;
          float nm2 = fmaxf(m2, v2);
          l2 = l2 * __expf(m2 - nm2) + (ok ? __expf(v2 - nm2) : 0.f);
          m2 = nm2;
        }
      }
      __syncthreads();
    }
  }

#pragma unroll
  for (int mk = 16; mk <= 32; mk <<= 1) {
    float pm = __shfl_xor(m1, mk, 64), pl = __shfl_xor(l1, mk, 64);
    float M = fmaxf(m1, pm);
    l1 = l1 * __expf(m1 - M) + pl * __expf(pm - M);
    m1 = M;
    pm = __shfl_xor(m2, mk, 64); pl = __shfl_xor(l2, mk, 64);
    M = fmaxf(m2, pm);
    l2 = l2 * __expf(m2 - M) + pl * __expf(pm - M);
    m2 = M;
  }
  const float c2 = lamv * l1 / l2;

  // pass 2: p' = relu(e1 - c2*e2), PV accumulate
  f32x4 accv[8];
#pragma unroll
  for (int n = 0; n < 8; ++n) accv[n] = zero4;
  float dln = 0.f;

  STAGE_K(0, t0 * 64);
  STAGE_V(0, t0 * 64);
  __syncthreads();
  {
    int cur = 0;
    for (int t = t0; t <= qb; ++t, cur ^= 1) {
      if (t < qb) {
        STAGE_K(cur ^ 1, (t + 1) * 64);
        STAGE_V(cur ^ 1, (t + 1) * 64);
      }
      const int kb0 = t * 64;
      unsigned* pw = (unsigned*)&Pw[w][0];
#pragma unroll
      for (int nt = 0; nt < 4; ++nt) {
        f32x4 s1 = zero4, s2 = zero4;
        s1 = MFMA16(KFRAG(cur, nt, lhi),      qf[0], s1);
        s1 = MFMA16(KFRAG(cur, nt, 4 + lhi),  qf[1], s1);
        s2 = MFMA16(KFRAG(cur, nt, 8 + lhi),  qf[2], s2);
        s2 = MFMA16(KFRAG(cur, nt, 12 + lhi), qf[3], s2);
        const int keyb = kb0 + nt * 16 + lhi * 4;
        float pr[4];
#pragma unroll
        for (int r = 0; r < 4; ++r) {
          const int key = keyb + r;
          const bool ok = (key <= myq) && (key > myq - 512);
          float e1 = ok ? __expf(s1[r] - m1) : 0.f;
          float e2 = ok ? __expf(s2[r] - m2) : 0.f;
          float p = e1 - c2 * e2;
          pr[r] = p > 0.f ? p : 0.f;
          dln += pr[r];
        }
        int pi = l15 * 36 + 8 * nt + 2 * lhi;
        pw[pi]     = packbf2(pr[0], pr[1]);
        pw[pi + 1] = packbf2(pr[2], pr[3]);
      }
#pragma unroll
      for (int kc = 0; kc < 2; ++kc) {
        short8 pa = *(const short8*)(&Pw[w][l15 * 72 + kc * 32 + lhi * 8]);
#pragma unroll
        for (int n = 0; n < 8; ++n)
          accv[n] = MFMA16(pa, VFRAG(cur, n, kc * 4 + lhi), accv[n]);
      }
      __syncthreads();
    }
  }

  dln += __shfl_xor(dln, 16, 64);
  dln += __shfl_xor(dln, 32, 64);

#pragma unroll
  for (int r = 0; r < 4; ++r) {
    int srcq = lhi * 4 + r;
    int src = (lane & 48) | srcq;
    float dq = __shfl(dln, src, 64);
    float lq = __shfl(l1, src, 64);
    float rinv = 1.f / (dq + lq * 1e-6f);
    int qo = qg + srcq;
#pragma unroll
    for (int n = 0; n < 8; ++n) {
      O[(size_t)qo * 2048 + h * 128 + n * 16 + l15] =
          __float2bfloat16(accv[n][r] * rinv);
    }
  }
#undef STAGE_K
#undef STAGE_V
#undef KFRAG
#undef VFRAG
}

// ================= launch =================
extern "C" void kernel_launch(void* const* d_in, const int* in_sizes, int n_in,
                              void* d_out, int out_size, void* d_ws, size_t ws_size,
                              hipStream_t stream)
{
  const float* x   = (const float*)d_in[0];
  const float* Wq  = (const float*)d_in[1];
  const float* Wk  = (const float*)d_in[2];
  const float* Wv  = (const float*)d_in[3];
  const float* Wo  = (const float*)d_in[4];
  const float* lam = (const float*)d_in[5];

  char* ws = (char*)d_ws;
  bf16* xb    = (bf16*)(ws);                       // [2048][2048]  8 MB
  bf16* Wqkvt = (bf16*)(ws + 8ull  * (1u << 20));  // [3072][2048] 12 MB
  bf16* Wot   = (bf16*)(ws + 20ull * (1u << 20));  // [2048][2048]  8 MB
  bf16* QKV   = (bf16*)(ws + 28ull * (1u << 20));  // [2048][3072] 12 MB
  bf16* ATT   = (bf16*)(ws + 40ull * (1u << 20));  // [2048][2048]  8 MB
  bf16* VT    = (bf16*)(ws + 48ull * (1u << 20));  // [512][2048]   2 MB

  prep_all<<<dim3(144, 32), 256, 0, stream>>>(x, Wq, Wk, Wv, Wo, xb, Wqkvt, Wot);
  gemm_bt<0><<<dim3(24, 16), 256, 0, stream>>>(xb, Wqkvt, QKV, 2048, 3072, 2048);
  rope2<<<1280, 256, 0, stream>>>(QKV);
  transpose_v<<<dim3(32, 8), 256, 0, stream>>>(QKV, VT);
  diff_attn<<<dim3(32, 16), 256, 0, stream>>>(QKV, VT, lam, ATT);
  gemm_bt<1><<<dim3(16, 16), 256, 0, stream>>>(ATT, Wot, d_out, 2048, 2048, 2048);
}